// Round 9
// baseline (321.486 us; speedup 1.0000x reference)
//
#include <hip/hip_runtime.h>
#include <stdint.h>

#define NN 100000   // nodes
#define NREL 3
#define NE 200000   // edges per relation
#define F 128       // feature dim (in = hid = out)
#define NQ 4096

#define NBUCK (NREL * NN)          // 300000 buckets
#define SCAN_PER_BLK 1024          // elements per scan block (256 thr x 4)
#define NSCANBLK ((NBUCK + SCAN_PER_BLK - 1) / SCAN_PER_BLK)  // 293
#define SCANB_PER 5                // ceil(293/64) elements per lane in scanB

typedef float fx4 __attribute__((ext_vector_type(4)));
typedef unsigned short u16x8 __attribute__((ext_vector_type(8)));
typedef __bf16 bf16x8 __attribute__((ext_vector_type(8)));

__device__ __forceinline__ unsigned short f2bf(float f) {
  uint32_t u = __builtin_bit_cast(uint32_t, f);
  uint32_t r = u + 0x7FFFu + ((u >> 16) & 1u);
  return (unsigned short)(r >> 16);
}
__device__ __forceinline__ float bf2f(unsigned short u) {
  return __builtin_bit_cast(float, (uint32_t)u << 16);
}

// ---- integer degree counts: cnt[0..3NN) = out-deg per rel, cnt[3NN..6NN) = in-deg ----
__global__ void cnt_kernel(const int* __restrict__ es, const int* __restrict__ ed,
                           int* __restrict__ cnt) {
  int i = blockIdx.x * blockDim.x + threadIdx.x;
  if (i >= NREL * NE) return;
  int r = i / NE;
  atomicAdd(&cnt[r * NN + es[i]], 1);
  atomicAdd(&cnt[NREL * NN + r * NN + ed[i]], 1);
}

// ---- deterministic hierarchical exclusive scan over cnt_in (no global atomics) ----
__global__ __launch_bounds__(256) void scanA_kernel(const int* __restrict__ cnt_in,
                                                    int* __restrict__ bsum) {
  int b = blockIdx.x, t = threadIdx.x;
  int base = b * SCAN_PER_BLK + t * 4;
  int s = 0;
#pragma unroll
  for (int k = 0; k < 4; ++k) {
    int i = base + k;
    if (i < NBUCK) s += cnt_in[i];
  }
#pragma unroll
  for (int d = 1; d < 64; d <<= 1) s += __shfl_xor(s, d);
  __shared__ int ws[4];
  if ((t & 63) == 0) ws[t >> 6] = s;
  __syncthreads();
  if (t == 0) bsum[b] = ws[0] + ws[1] + ws[2] + ws[3];
}

__global__ void scanB_kernel(int* __restrict__ bsum) {
  int lane = threadIdx.x;  // 64 threads
  int v[SCANB_PER];
  int s = 0;
#pragma unroll
  for (int k = 0; k < SCANB_PER; ++k) {
    int i = lane * SCANB_PER + k;
    v[k] = (i < NSCANBLK) ? bsum[i] : 0;
    s += v[k];
  }
  int sc = s;
#pragma unroll
  for (int d = 1; d < 64; d <<= 1) {
    int o = __shfl_up(sc, d);
    if (lane >= d) sc += o;
  }
  int excl = sc - s;
#pragma unroll
  for (int k = 0; k < SCANB_PER; ++k) {
    int i = lane * SCANB_PER + k;
    if (i < NSCANBLK) { bsum[i] = excl; excl += v[k]; }
  }
}

__global__ __launch_bounds__(256) void scanC_kernel(const int* __restrict__ cnt_in,
                                                    const int* __restrict__ bsum,
                                                    int2* __restrict__ scb,
                                                    int* __restrict__ fill) {
  int b = blockIdx.x, t = threadIdx.x;
  int base = b * SCAN_PER_BLK + t * 4;
  int c[4];
  int s = 0;
#pragma unroll
  for (int k = 0; k < 4; ++k) {
    int i = base + k;
    c[k] = (i < NBUCK) ? cnt_in[i] : 0;
    s += c[k];
  }
  int lane = t & 63, w = t >> 6;
  int sc = s;
#pragma unroll
  for (int d = 1; d < 64; d <<= 1) {
    int o = __shfl_up(sc, d);
    if (lane >= d) sc += o;
  }
  int thr_excl = sc - s;
  __shared__ int wtot[4];
  if (lane == 63) wtot[w] = sc;
  __syncthreads();
  int wave_off = 0;
#pragma unroll
  for (int ww = 0; ww < 3; ++ww) wave_off += (ww < w) ? wtot[ww] : 0;
  int start = bsum[b] + wave_off + thr_excl;
#pragma unroll
  for (int k = 0; k < 4; ++k) {
    int i = base + k;
    if (i < NBUCK) {
      scb[i] = make_int2(start, c[k]);
      fill[i] = 0;
      start += c[k];
    }
  }
}

// place each edge into its dst bucket; payload = {src, w = rsqrt(outdeg)*rsqrt(indeg)}
__global__ void fill_kernel(const int* __restrict__ es, const int* __restrict__ ed,
                            const int* __restrict__ cnt,
                            const int2* __restrict__ scb, int* __restrict__ fill,
                            int2* __restrict__ epay) {
  int i = blockIdx.x * blockDim.x + threadIdx.x;
  if (i >= NREL * NE) return;
  int r = i / NE;
  int s = es[i], d = ed[i];
  int b = r * NN + d;
  int2 m = scb[b];
  int pos = m.x + atomicAdd(&fill[b], 1);
  int co = cnt[r * NN + s];
  float w = rsqrtf((float)co) * rsqrtf((float)m.y);
  epay[pos] = make_int2(s, __builtin_bit_cast(int, w));
}

// Wtb[layer][rel][n][k] = bf16(W[layer][rel][k][n])
__global__ void wcvt_kernel(const float* __restrict__ W1, const float* __restrict__ W2,
                            unsigned short* __restrict__ Wtb) {
  int i = blockIdx.x * blockDim.x + threadIdx.x;
  if (i >= 2 * NREL * F * F) return;
  int l = i / (NREL * F * F);
  int rem = i % (NREL * F * F);
  int r = rem / (F * F);
  int nk = rem % (F * F);
  int n = nk >> 7, k = nk & 127;
  const float* W = l ? W2 : W1;
  Wtb[i] = f2bf(W[r * F * F + k * F + n]);
}

// bsum[l][f] = sum_r b_l[r][f]
__global__ void bias_kernel(const float* __restrict__ b1, const float* __restrict__ b2,
                            float* __restrict__ bsum) {
  int t = threadIdx.x;  // 256
  int l = t >> 7, f = t & 127;
  const float* b = l ? b2 : b1;
  bsum[l * F + f] = b[f] + b[F + f] + b[2 * F + f];
}

// X (f32) -> Xb (bf16)
__global__ void cvtx_kernel(const float* __restrict__ x, unsigned short* __restrict__ xb) {
  int i = blockIdx.x * blockDim.x + threadIdx.x;  // one per 8 elems
  const float* p = x + (size_t)i * 8;
  unsigned short tmp[8];
#pragma unroll
  for (int e = 0; e < 8; ++e) tmp[e] = f2bf(p[e]);
  *reinterpret_cast<u16x8*>(xb + (size_t)i * 8) = *reinterpret_cast<u16x8*>(tmp);
}

// ---- fused layer: per relation, gather+aggregate a 128x128 bf16 Z-tile into LDS
//      (double-buffered), MFMA with W_r fragments held in registers, accumulate
//      across relations in VGPRs, tanh epilogue. Z never touches global memory.
// 512 thr = 8 waves. Gather phase: 32 quarter-waves x 16 lanes. MFMA: 2m x 4n waves.
#define GBM 128
#define LDP 136
__global__ __launch_bounds__(512) void fused_kernel(const unsigned short* __restrict__ X,
                                                    const int2* __restrict__ scb,
                                                    const int2* __restrict__ epay,
                                                    const int* __restrict__ qsrc,
                                                    const int* __restrict__ qdst,
                                                    const unsigned short* __restrict__ Wt3,
                                                    const float* __restrict__ bsum,
                                                    void* __restrict__ outp,
                                                    int M, int out_f32) {
  __shared__ unsigned short Ztd[2][GBM * LDP];  // double-buffered, ~69.6 KB
  const int t = threadIdx.x;
  const int m0 = blockIdx.x * GBM;
  const int lane = t & 63, w = t >> 6;
  const int wm = w >> 2, wn = w & 3;        // 2m x 4n wave grid (MFMA phase)
  const int r0 = lane & 15, kq = lane >> 4;
  const int qw = t >> 4, j = t & 15;        // gather phase: quarter-wave id, feature octet

  fx4 acc[4][2];
#pragma unroll
  for (int mt = 0; mt < 4; ++mt)
#pragma unroll
    for (int nt = 0; nt < 2; ++nt) acc[mt][nt] = (fx4){0.f, 0.f, 0.f, 0.f};

  for (int r = 0; r < NREL; ++r) {
    unsigned short* Zc = &Ztd[r & 1][0];

    // W_r fragments: global -> regs, issued up front; consumed after the barrier
    // (global->reg prefetch across a barrier is the R7-proven wreg pattern)
    bf16x8 bfrag[2][4];
    const unsigned short* Wt = Wt3 + (size_t)r * F * F;
#pragma unroll
    for (int nt = 0; nt < 2; ++nt)
#pragma unroll
      for (int kb = 0; kb < 4; ++kb)
        bfrag[nt][kb] = __builtin_bit_cast(bf16x8,
            *reinterpret_cast<const u16x8*>(
                Wt + (wn * 32 + nt * 16 + r0) * F + (4 * kb + kq) * 8));

    // phase 1: build bf16 Z tile for relation r (f32 accumulate, one bf16 round)
    for (int it = 0; it < 4; ++it) {
      int rr = it * 32 + qw;
      int m = m0 + rr;
      float ps[8];
#pragma unroll
      for (int k = 0; k < 8; ++k) ps[k] = 0.f;
      if (m < M) {
        int n = qsrc ? ((m < NQ) ? qsrc[m] : qdst[m - NQ]) : m;
        int2 meta = scb[r * NN + n];
        const int2* ep = epay + meta.x;
        const int c = meta.y;
        int i = 0;
        for (; i + 2 <= c; i += 2) {
          int2 p0 = ep[i], p1 = ep[i + 1];
          float w0 = __builtin_bit_cast(float, p0.y);
          float w1 = __builtin_bit_cast(float, p1.y);
          u16x8 v0 = *reinterpret_cast<const u16x8*>(X + ((size_t)p0.x << 7) + j * 8);
          u16x8 v1 = *reinterpret_cast<const u16x8*>(X + ((size_t)p1.x << 7) + j * 8);
#pragma unroll
          for (int k = 0; k < 8; ++k)
            ps[k] = fmaf(bf2f(v1[k]), w1, fmaf(bf2f(v0[k]), w0, ps[k]));
        }
        if (i < c) {
          int2 p0 = ep[i];
          float w0 = __builtin_bit_cast(float, p0.y);
          u16x8 v0 = *reinterpret_cast<const u16x8*>(X + ((size_t)p0.x << 7) + j * 8);
#pragma unroll
          for (int k = 0; k < 8; ++k) ps[k] = fmaf(bf2f(v0[k]), w0, ps[k]);
        }
      }
      unsigned short tmp[8];
#pragma unroll
      for (int k = 0; k < 8; ++k) tmp[k] = f2bf(ps[k]);
      *reinterpret_cast<u16x8*>(&Zc[rr * LDP + j * 8]) = *reinterpret_cast<u16x8*>(tmp);
    }

    __syncthreads();  // Z tile (buffer r&1) fully written

    // phase 2: MFMA over this rel's K=128 from buffer r&1
#pragma unroll
    for (int kb = 0; kb < 4; ++kb) {
      const int cs = (4 * kb + kq) * 8;
      bf16x8 a[4];
#pragma unroll
      for (int mt = 0; mt < 4; ++mt)
        a[mt] = __builtin_bit_cast(bf16x8,
            *reinterpret_cast<const u16x8*>(&Zc[(wm * 64 + mt * 16 + r0) * LDP + cs]));
#pragma unroll
      for (int mt = 0; mt < 4; ++mt)
#pragma unroll
        for (int nt = 0; nt < 2; ++nt)
          acc[mt][nt] = __builtin_amdgcn_mfma_f32_16x16x32_bf16(a[mt], bfrag[nt][kb],
                                                                acc[mt][nt], 0, 0, 0);
    }

    __syncthreads();  // all reads of buffer r&1 done before it is reused (r+2)
  }

  // epilogue: C/D layout col = lane&15, row = (lane>>4)*4 + reg; +bias, tanh
#pragma unroll
  for (int mt = 0; mt < 4; ++mt) {
    const int rbase = m0 + wm * 64 + mt * 16 + kq * 4;
#pragma unroll
    for (int nt = 0; nt < 2; ++nt) {
      int col = wn * 32 + nt * 16 + r0;
      float bb = bsum[col];
#pragma unroll
      for (int reg = 0; reg < 4; ++reg) {
        int gm = rbase + reg;
        if (gm < M) {
          float v = tanhf(acc[mt][nt][reg] + bb);
          if (out_f32) {
            ((float*)outp)[(size_t)gm * F + col] = v;
          } else {
            ((unsigned short*)outp)[(size_t)gm * F + col] = f2bf(v);
          }
        }
      }
    }
  }
}

extern "C" void kernel_launch(void* const* d_in, const int* in_sizes, int n_in,
                              void* d_out, int out_size, void* d_ws, size_t ws_size,
                              hipStream_t stream) {
  const float* emb = (const float*)d_in[0];
  const float* W1  = (const float*)d_in[1];
  const float* b1  = (const float*)d_in[2];
  const float* W2  = (const float*)d_in[3];
  const float* b2  = (const float*)d_in[4];
  const int* e_src = (const int*)d_in[5];
  const int* e_dst = (const int*)d_in[6];
  const int* qsrc  = (const int*)d_in[7];
  const int* qdst  = (const int*)d_in[8];
  float* out = (float*)d_out;

  char* p = (char*)d_ws;
  size_t off = 0;
  auto take = [&](size_t n) { void* q = p + off; off = (off + n + 255) & ~(size_t)255; return q; };
  int* cnt    = (int*)take(2ull * NREL * NN * 4);       // [out|in] counts
  int* blksum = (int*)take((size_t)NSCANBLK * 4);       // scan block sums
  int2* scb   = (int2*)take((size_t)NBUCK * 8);         // {start, cnt} per bucket
  int* fill   = (int*)take((size_t)NBUCK * 4);
  int2* epay  = (int2*)take((size_t)NREL * NE * 8);     // {src, w}
  unsigned short* Wtb = (unsigned short*)take(2ull * NREL * F * F * 2);
  float* bsum = (float*)take(2ull * F * 4);
  unsigned short* Xb  = (unsigned short*)take((size_t)NN * F * 2);   // h0 (bf16 emb)
  unsigned short* Xb2 = (unsigned short*)take((size_t)NN * F * 2);   // h1 (bf16)

  int* cnt_in = cnt + (size_t)NREL * NN;

  hipMemsetAsync(cnt, 0, 2ull * NREL * NN * 4, stream);
  cnt_kernel<<<(NREL * NE + 255) / 256, 256, 0, stream>>>(e_src, e_dst, cnt);
  scanA_kernel<<<NSCANBLK, 256, 0, stream>>>(cnt_in, blksum);
  scanB_kernel<<<1, 64, 0, stream>>>(blksum);
  scanC_kernel<<<NSCANBLK, 256, 0, stream>>>(cnt_in, blksum, scb, fill);
  fill_kernel<<<(NREL * NE + 255) / 256, 256, 0, stream>>>(e_src, e_dst, cnt, scb, fill, epay);
  wcvt_kernel<<<(2 * NREL * F * F + 255) / 256, 256, 0, stream>>>(W1, W2, Wtb);
  bias_kernel<<<1, 256, 0, stream>>>(b1, b2, bsum);
  cvtx_kernel<<<(NN * F / 8 + 255) / 256, 256, 0, stream>>>(emb, Xb);

  // layer 1: all nodes, bf16 h1 -> Xb2 (separate buffer: gather source Xb still live)
  fused_kernel<<<(NN + GBM - 1) / GBM, 512, 0, stream>>>(
      Xb, scb, epay, nullptr, nullptr, Wtb, bsum, Xb2, NN, 0);

  // layer 2: only the 2*NQ query slots, f32 straight to d_out
  fused_kernel<<<(2 * NQ + GBM - 1) / GBM, 512, 0, stream>>>(
      Xb2, scb, epay, qsrc, qdst, Wtb + (size_t)NREL * F * F, bsum + F, out, 2 * NQ, 1);
}

// Round 10
// 279.825 us; speedup vs baseline: 1.1489x; 1.1489x over previous
//
#include <hip/hip_runtime.h>
#include <stdint.h>

#define NN 100000   // nodes
#define NREL 3
#define NE 200000   // edges per relation
#define F 128       // feature dim (in = hid = out)
#define NQ 4096

#define NBUCK (NREL * NN)          // 300000 buckets
#define SCAN_PER_BLK 1024          // elements per scan block (256 thr x 4)
#define NSCANBLK ((NBUCK + SCAN_PER_BLK - 1) / SCAN_PER_BLK)  // 293
#define SCANB_PER 5                // ceil(293/64) elements per lane in scanB

typedef float fx4 __attribute__((ext_vector_type(4)));
typedef unsigned short u16x8 __attribute__((ext_vector_type(8)));
typedef __bf16 bf16x8 __attribute__((ext_vector_type(8)));

__device__ __forceinline__ unsigned short f2bf(float f) {
  uint32_t u = __builtin_bit_cast(uint32_t, f);
  uint32_t r = u + 0x7FFFu + ((u >> 16) & 1u);
  return (unsigned short)(r >> 16);
}
__device__ __forceinline__ float bf2f(unsigned short u) {
  return __builtin_bit_cast(float, (uint32_t)u << 16);
}

// ---- integer degree counts: cnt[0..3NN) = out-deg per rel, cnt[3NN..6NN) = in-deg ----
__global__ void cnt_kernel(const int* __restrict__ es, const int* __restrict__ ed,
                           int* __restrict__ cnt) {
  int i = blockIdx.x * blockDim.x + threadIdx.x;
  if (i >= NREL * NE) return;
  int r = i / NE;
  atomicAdd(&cnt[r * NN + es[i]], 1);
  atomicAdd(&cnt[NREL * NN + r * NN + ed[i]], 1);
}

// ---- deterministic hierarchical exclusive scan over cnt_in (no global atomics) ----
__global__ __launch_bounds__(256) void scanA_kernel(const int* __restrict__ cnt_in,
                                                    int* __restrict__ bsum) {
  int b = blockIdx.x, t = threadIdx.x;
  int base = b * SCAN_PER_BLK + t * 4;
  int s = 0;
#pragma unroll
  for (int k = 0; k < 4; ++k) {
    int i = base + k;
    if (i < NBUCK) s += cnt_in[i];
  }
#pragma unroll
  for (int d = 1; d < 64; d <<= 1) s += __shfl_xor(s, d);
  __shared__ int ws[4];
  if ((t & 63) == 0) ws[t >> 6] = s;
  __syncthreads();
  if (t == 0) bsum[b] = ws[0] + ws[1] + ws[2] + ws[3];
}

__global__ void scanB_kernel(int* __restrict__ bsum) {
  int lane = threadIdx.x;  // 64 threads
  int v[SCANB_PER];
  int s = 0;
#pragma unroll
  for (int k = 0; k < SCANB_PER; ++k) {
    int i = lane * SCANB_PER + k;
    v[k] = (i < NSCANBLK) ? bsum[i] : 0;
    s += v[k];
  }
  int sc = s;
#pragma unroll
  for (int d = 1; d < 64; d <<= 1) {
    int o = __shfl_up(sc, d);
    if (lane >= d) sc += o;
  }
  int excl = sc - s;
#pragma unroll
  for (int k = 0; k < SCANB_PER; ++k) {
    int i = lane * SCANB_PER + k;
    if (i < NSCANBLK) { bsum[i] = excl; excl += v[k]; }
  }
}

__global__ __launch_bounds__(256) void scanC_kernel(const int* __restrict__ cnt_in,
                                                    const int* __restrict__ bsum,
                                                    int2* __restrict__ scb,
                                                    int* __restrict__ fill) {
  int b = blockIdx.x, t = threadIdx.x;
  int base = b * SCAN_PER_BLK + t * 4;
  int c[4];
  int s = 0;
#pragma unroll
  for (int k = 0; k < 4; ++k) {
    int i = base + k;
    c[k] = (i < NBUCK) ? cnt_in[i] : 0;
    s += c[k];
  }
  int lane = t & 63, w = t >> 6;
  int sc = s;
#pragma unroll
  for (int d = 1; d < 64; d <<= 1) {
    int o = __shfl_up(sc, d);
    if (lane >= d) sc += o;
  }
  int thr_excl = sc - s;
  __shared__ int wtot[4];
  if (lane == 63) wtot[w] = sc;
  __syncthreads();
  int wave_off = 0;
#pragma unroll
  for (int ww = 0; ww < 3; ++ww) wave_off += (ww < w) ? wtot[ww] : 0;
  int start = bsum[b] + wave_off + thr_excl;
#pragma unroll
  for (int k = 0; k < 4; ++k) {
    int i = base + k;
    if (i < NBUCK) {
      scb[i] = make_int2(start, c[k]);
      fill[i] = 0;
      start += c[k];
    }
  }
}

// place each edge into its dst bucket; payload = {src, w = rsqrt(outdeg)*rsqrt(indeg)}
__global__ void fill_kernel(const int* __restrict__ es, const int* __restrict__ ed,
                            const int* __restrict__ cnt,
                            const int2* __restrict__ scb, int* __restrict__ fill,
                            int2* __restrict__ epay) {
  int i = blockIdx.x * blockDim.x + threadIdx.x;
  if (i >= NREL * NE) return;
  int r = i / NE;
  int s = es[i], d = ed[i];
  int b = r * NN + d;
  int2 m = scb[b];
  int pos = m.x + atomicAdd(&fill[b], 1);
  int co = cnt[r * NN + s];
  float w = rsqrtf((float)co) * rsqrtf((float)m.y);
  epay[pos] = make_int2(s, __builtin_bit_cast(int, w));
}

// Wtb[layer][rel][n][k] = bf16(W[layer][rel][k][n])
__global__ void wcvt_kernel(const float* __restrict__ W1, const float* __restrict__ W2,
                            unsigned short* __restrict__ Wtb) {
  int i = blockIdx.x * blockDim.x + threadIdx.x;
  if (i >= 2 * NREL * F * F) return;
  int l = i / (NREL * F * F);
  int rem = i % (NREL * F * F);
  int r = rem / (F * F);
  int nk = rem % (F * F);
  int n = nk >> 7, k = nk & 127;
  const float* W = l ? W2 : W1;
  Wtb[i] = f2bf(W[r * F * F + k * F + n]);
}

// bsum[l][f] = sum_r b_l[r][f]
__global__ void bias_kernel(const float* __restrict__ b1, const float* __restrict__ b2,
                            float* __restrict__ bsum) {
  int t = threadIdx.x;  // 256
  int l = t >> 7, f = t & 127;
  const float* b = l ? b2 : b1;
  bsum[l * F + f] = b[f] + b[F + f] + b[2 * F + f];
}

// X (f32) -> Xb (bf16)
__global__ void cvtx_kernel(const float* __restrict__ x, unsigned short* __restrict__ xb) {
  int i = blockIdx.x * blockDim.x + threadIdx.x;  // one per 8 elems
  const float* p = x + (size_t)i * 8;
  unsigned short tmp[8];
#pragma unroll
  for (int e = 0; e < 8; ++e) tmp[e] = f2bf(p[e]);
  *reinterpret_cast<u16x8*>(xb + (size_t)i * 8) = *reinterpret_cast<u16x8*>(tmp);
}

// ---- aggregate-first: Z[r][m][f] = sum_{e in bucket(r,n)} w_e * X[src_e][f]
// 16 lanes per m-row (j = lane&15 -> features j*8..j*8+7), 4 rows per wave.
__global__ __launch_bounds__(256) void aggz_kernel(const unsigned short* __restrict__ X,
                                                   const int2* __restrict__ scb,
                                                   const int2* __restrict__ epay,
                                                   const int* __restrict__ qsrc,
                                                   const int* __restrict__ qdst,
                                                   unsigned short* __restrict__ Z, int M) {
  const int r = blockIdx.y;
  const int t = threadIdx.x;
  const int lane = t & 63;
  const int m = blockIdx.x * 16 + (t >> 6) * 4 + (lane >> 4);
  const int j = lane & 15;
  if (m >= M) return;
  int n = qsrc ? ((m < NQ) ? qsrc[m] : qdst[m - NQ]) : m;
  int2 meta = scb[r * NN + n];
  const int2* ep = epay + meta.x;
  const int c = meta.y;

  float ps[8];
#pragma unroll
  for (int k = 0; k < 8; ++k) ps[k] = 0.f;

  int i = 0;
  for (; i + 2 <= c; i += 2) {
    int2 p0 = ep[i], p1 = ep[i + 1];
    float w0 = __builtin_bit_cast(float, p0.y);
    float w1 = __builtin_bit_cast(float, p1.y);
    u16x8 v0 = *reinterpret_cast<const u16x8*>(X + ((size_t)p0.x << 7) + j * 8);
    u16x8 v1 = *reinterpret_cast<const u16x8*>(X + ((size_t)p1.x << 7) + j * 8);
#pragma unroll
    for (int k = 0; k < 8; ++k)
      ps[k] = fmaf(bf2f(v1[k]), w1, fmaf(bf2f(v0[k]), w0, ps[k]));
  }
  if (i < c) {
    int2 p0 = ep[i];
    float w0 = __builtin_bit_cast(float, p0.y);
    u16x8 v0 = *reinterpret_cast<const u16x8*>(X + ((size_t)p0.x << 7) + j * 8);
#pragma unroll
    for (int k = 0; k < 8; ++k) ps[k] = fmaf(bf2f(v0[k]), w0, ps[k]);
  }

  unsigned short tmp[8];
#pragma unroll
  for (int k = 0; k < 8; ++k) tmp[k] = f2bf(ps[k]);
  *reinterpret_cast<u16x8*>(Z + (((size_t)r * M + m) << 7) + j * 8) =
      *reinterpret_cast<u16x8*>(tmp);
}

// ---- LDS-free streaming fused GEMM: out[m] = tanh( sum_r Z[r][m] @ W_r + bsum )
// wave = 32 output rows x 128 cols; A and W fragments loaded global->reg->MFMA.
// No LDS, no barriers: latency hidden by ILP (10 loads / 16 MFMAs per k-chunk)
// and TLP (781 independent blocks). W stays per-XCD-L2 resident (96 KB).
#define SROWS 32                  // rows per wave
#define SGBM 128                  // rows per block (4 waves)
__global__ __launch_bounds__(256) void gemms_kernel(const unsigned short* __restrict__ Z,
                                                    const unsigned short* __restrict__ Wt3,
                                                    const float* __restrict__ bsum,
                                                    void* __restrict__ outp,
                                                    int M, int out_f32) {
  const int t = threadIdx.x;
  const int lane = t & 63, w = t >> 6;
  const int r0 = lane & 15, kq = lane >> 4;
  const int mb = blockIdx.x * SGBM + w * SROWS;

  fx4 acc[2][8];
#pragma unroll
  for (int mt = 0; mt < 2; ++mt)
#pragma unroll
    for (int nt = 0; nt < 8; ++nt) acc[mt][nt] = (fx4){0.f, 0.f, 0.f, 0.f};

  for (int r = 0; r < NREL; ++r) {
    const unsigned short* Zr = Z + (size_t)r * M * F;
    const unsigned short* Wt = Wt3 + (size_t)r * F * F;
#pragma unroll
    for (int kb = 0; kb < 4; ++kb) {
      const int kc = kb * 32 + kq * 8;
      bf16x8 a[2], b[8];
#pragma unroll
      for (int mt = 0; mt < 2; ++mt) {
        int row = mb + mt * 16 + r0;
        u16x8 raw = (row < M)
            ? *reinterpret_cast<const u16x8*>(Zr + (size_t)row * F + kc)
            : (u16x8)0;
        a[mt] = __builtin_bit_cast(bf16x8, raw);
      }
#pragma unroll
      for (int nt = 0; nt < 8; ++nt)
        b[nt] = __builtin_bit_cast(bf16x8,
            *reinterpret_cast<const u16x8*>(Wt + (nt * 16 + r0) * F + kc));
#pragma unroll
      for (int mt = 0; mt < 2; ++mt)
#pragma unroll
        for (int nt = 0; nt < 8; ++nt)
          acc[mt][nt] = __builtin_amdgcn_mfma_f32_16x16x32_bf16(a[mt], b[nt],
                                                                acc[mt][nt], 0, 0, 0);
    }
  }

  // epilogue: C/D layout col = lane&15, row = (lane>>4)*4 + reg; +bias, tanh
#pragma unroll
  for (int mt = 0; mt < 2; ++mt) {
    const int rbase = mb + mt * 16 + kq * 4;
#pragma unroll
    for (int nt = 0; nt < 8; ++nt) {
      int col = nt * 16 + r0;
      float bb = bsum[col];
#pragma unroll
      for (int reg = 0; reg < 4; ++reg) {
        int gm = rbase + reg;
        if (gm < M) {
          float v = tanhf(acc[mt][nt][reg] + bb);
          if (out_f32) {
            ((float*)outp)[(size_t)gm * F + col] = v;
          } else {
            ((unsigned short*)outp)[(size_t)gm * F + col] = f2bf(v);
          }
        }
      }
    }
  }
}

extern "C" void kernel_launch(void* const* d_in, const int* in_sizes, int n_in,
                              void* d_out, int out_size, void* d_ws, size_t ws_size,
                              hipStream_t stream) {
  const float* emb = (const float*)d_in[0];
  const float* W1  = (const float*)d_in[1];
  const float* b1  = (const float*)d_in[2];
  const float* W2  = (const float*)d_in[3];
  const float* b2  = (const float*)d_in[4];
  const int* e_src = (const int*)d_in[5];
  const int* e_dst = (const int*)d_in[6];
  const int* qsrc  = (const int*)d_in[7];
  const int* qdst  = (const int*)d_in[8];
  float* out = (float*)d_out;

  char* p = (char*)d_ws;
  size_t off = 0;
  auto take = [&](size_t n) { void* q = p + off; off = (off + n + 255) & ~(size_t)255; return q; };
  int* cnt    = (int*)take(2ull * NREL * NN * 4);       // [out|in] counts
  int* blksum = (int*)take((size_t)NSCANBLK * 4);       // scan block sums
  int2* scb   = (int2*)take((size_t)NBUCK * 8);         // {start, cnt} per bucket
  int* fill   = (int*)take((size_t)NBUCK * 4);
  int2* epay  = (int2*)take((size_t)NREL * NE * 8);     // {src, w}
  unsigned short* Wtb = (unsigned short*)take(2ull * NREL * F * F * 2);
  float* bsum = (float*)take(2ull * F * 4);
  unsigned short* Xb  = (unsigned short*)take((size_t)NN * F * 2);   // h0 / h1 (bf16)
  unsigned short* Z   = (unsigned short*)take((size_t)NREL * NN * F * 2);

  int* cnt_in = cnt + (size_t)NREL * NN;

  hipMemsetAsync(cnt, 0, 2ull * NREL * NN * 4, stream);
  cnt_kernel<<<(NREL * NE + 255) / 256, 256, 0, stream>>>(e_src, e_dst, cnt);
  scanA_kernel<<<NSCANBLK, 256, 0, stream>>>(cnt_in, blksum);
  scanB_kernel<<<1, 64, 0, stream>>>(blksum);
  scanC_kernel<<<NSCANBLK, 256, 0, stream>>>(cnt_in, blksum, scb, fill);
  fill_kernel<<<(NREL * NE + 255) / 256, 256, 0, stream>>>(e_src, e_dst, cnt, scb, fill, epay);
  wcvt_kernel<<<(2 * NREL * F * F + 255) / 256, 256, 0, stream>>>(W1, W2, Wtb);
  bias_kernel<<<1, 256, 0, stream>>>(b1, b2, bsum);
  cvtx_kernel<<<(NN * F / 8 + 255) / 256, 256, 0, stream>>>(emb, Xb);

  // layer 1: Z1 at all nodes, streaming GEMM writes bf16 h1 back into Xb
  dim3 ag1((NN + 15) / 16, NREL);
  aggz_kernel<<<ag1, 256, 0, stream>>>(Xb, scb, epay, nullptr, nullptr, Z, NN);
  gemms_kernel<<<(NN + SGBM - 1) / SGBM, 256, 0, stream>>>(Z, Wtb, bsum, Xb, NN, 0);

  // layer 2: only the 2*NQ query slots
  dim3 ag2((2 * NQ + 15) / 16, NREL);
  aggz_kernel<<<ag2, 256, 0, stream>>>(Xb, scb, epay, qsrc, qdst, Z, 2 * NQ);
  gemms_kernel<<<(2 * NQ + SGBM - 1) / SGBM, 256, 0, stream>>>(
      Z, Wtb + (size_t)NREL * F * F, bsum + F, out, 2 * NQ, 1);
}

// Round 11
// 220.204 us; speedup vs baseline: 1.4599x; 1.2708x over previous
//
#include <hip/hip_runtime.h>
#include <stdint.h>

#define NN 100000   // nodes
#define NREL 3
#define NE 200000   // edges per relation
#define F 128       // feature dim (in = hid = out)
#define NQ 4096

#define NBUCK (NREL * NN)          // 300000 buckets
#define SCAN_PER_BLK 1024          // elements per scan block (256 thr x 4)
#define NSCANBLK ((NBUCK + SCAN_PER_BLK - 1) / SCAN_PER_BLK)  // 293
#define SCANB_PER 5                // ceil(293/64) elements per lane in scanB

typedef float fx4 __attribute__((ext_vector_type(4)));
typedef unsigned short u16x8 __attribute__((ext_vector_type(8)));
typedef __bf16 bf16x8 __attribute__((ext_vector_type(8)));

__device__ __forceinline__ unsigned short f2bf(float f) {
  uint32_t u = __builtin_bit_cast(uint32_t, f);
  uint32_t r = u + 0x7FFFu + ((u >> 16) & 1u);
  return (unsigned short)(r >> 16);
}
__device__ __forceinline__ float bf2f(unsigned short u) {
  return __builtin_bit_cast(float, (uint32_t)u << 16);
}

// ---- integer degree counts: cnt[0..3NN) = out-deg per rel, cnt[3NN..6NN) = in-deg ----
__global__ void cnt_kernel(const int* __restrict__ es, const int* __restrict__ ed,
                           int* __restrict__ cnt) {
  int i = blockIdx.x * blockDim.x + threadIdx.x;
  if (i >= NREL * NE) return;
  int r = i / NE;
  atomicAdd(&cnt[r * NN + es[i]], 1);
  atomicAdd(&cnt[NREL * NN + r * NN + ed[i]], 1);
}

// ---- deterministic hierarchical exclusive scan over cnt_in (no global atomics) ----
__global__ __launch_bounds__(256) void scanA_kernel(const int* __restrict__ cnt_in,
                                                    int* __restrict__ bsum) {
  int b = blockIdx.x, t = threadIdx.x;
  int base = b * SCAN_PER_BLK + t * 4;
  int s = 0;
#pragma unroll
  for (int k = 0; k < 4; ++k) {
    int i = base + k;
    if (i < NBUCK) s += cnt_in[i];
  }
#pragma unroll
  for (int d = 1; d < 64; d <<= 1) s += __shfl_xor(s, d);
  __shared__ int ws[4];
  if ((t & 63) == 0) ws[t >> 6] = s;
  __syncthreads();
  if (t == 0) bsum[b] = ws[0] + ws[1] + ws[2] + ws[3];
}

__global__ void scanB_kernel(int* __restrict__ bsum) {
  int lane = threadIdx.x;  // 64 threads
  int v[SCANB_PER];
  int s = 0;
#pragma unroll
  for (int k = 0; k < SCANB_PER; ++k) {
    int i = lane * SCANB_PER + k;
    v[k] = (i < NSCANBLK) ? bsum[i] : 0;
    s += v[k];
  }
  int sc = s;
#pragma unroll
  for (int d = 1; d < 64; d <<= 1) {
    int o = __shfl_up(sc, d);
    if (lane >= d) sc += o;
  }
  int excl = sc - s;
#pragma unroll
  for (int k = 0; k < SCANB_PER; ++k) {
    int i = lane * SCANB_PER + k;
    if (i < NSCANBLK) { bsum[i] = excl; excl += v[k]; }
  }
}

__global__ __launch_bounds__(256) void scanC_kernel(const int* __restrict__ cnt_in,
                                                    const int* __restrict__ bsum,
                                                    int2* __restrict__ scb,
                                                    int* __restrict__ fill) {
  int b = blockIdx.x, t = threadIdx.x;
  int base = b * SCAN_PER_BLK + t * 4;
  int c[4];
  int s = 0;
#pragma unroll
  for (int k = 0; k < 4; ++k) {
    int i = base + k;
    c[k] = (i < NBUCK) ? cnt_in[i] : 0;
    s += c[k];
  }
  int lane = t & 63, w = t >> 6;
  int sc = s;
#pragma unroll
  for (int d = 1; d < 64; d <<= 1) {
    int o = __shfl_up(sc, d);
    if (lane >= d) sc += o;
  }
  int thr_excl = sc - s;
  __shared__ int wtot[4];
  if (lane == 63) wtot[w] = sc;
  __syncthreads();
  int wave_off = 0;
#pragma unroll
  for (int ww = 0; ww < 3; ++ww) wave_off += (ww < w) ? wtot[ww] : 0;
  int start = bsum[b] + wave_off + thr_excl;
#pragma unroll
  for (int k = 0; k < 4; ++k) {
    int i = base + k;
    if (i < NBUCK) {
      scb[i] = make_int2(start, c[k]);
      fill[i] = 0;
      start += c[k];
    }
  }
}

// place each edge into its dst bucket; payload = {src, w = rsqrt(outdeg)*rsqrt(indeg)}
__global__ void fill_kernel(const int* __restrict__ es, const int* __restrict__ ed,
                            const int* __restrict__ cnt,
                            const int2* __restrict__ scb, int* __restrict__ fill,
                            int2* __restrict__ epay) {
  int i = blockIdx.x * blockDim.x + threadIdx.x;
  if (i >= NREL * NE) return;
  int r = i / NE;
  int s = es[i], d = ed[i];
  int b = r * NN + d;
  int2 m = scb[b];
  int pos = m.x + atomicAdd(&fill[b], 1);
  int co = cnt[r * NN + s];
  float w = rsqrtf((float)co) * rsqrtf((float)m.y);
  epay[pos] = make_int2(s, __builtin_bit_cast(int, w));
}

// Wtb[layer][rel][n][k] = bf16(W[layer][rel][k][n])
__global__ void wcvt_kernel(const float* __restrict__ W1, const float* __restrict__ W2,
                            unsigned short* __restrict__ Wtb) {
  int i = blockIdx.x * blockDim.x + threadIdx.x;
  if (i >= 2 * NREL * F * F) return;
  int l = i / (NREL * F * F);
  int rem = i % (NREL * F * F);
  int r = rem / (F * F);
  int nk = rem % (F * F);
  int n = nk >> 7, k = nk & 127;
  const float* W = l ? W2 : W1;
  Wtb[i] = f2bf(W[r * F * F + k * F + n]);
}

// bsum[l][f] = sum_r b_l[r][f]
__global__ void bias_kernel(const float* __restrict__ b1, const float* __restrict__ b2,
                            float* __restrict__ bsum) {
  int t = threadIdx.x;  // 256
  int l = t >> 7, f = t & 127;
  const float* b = l ? b2 : b1;
  bsum[l * F + f] = b[f] + b[F + f] + b[2 * F + f];
}

// X (f32) -> Xb (bf16)
__global__ void cvtx_kernel(const float* __restrict__ x, unsigned short* __restrict__ xb) {
  int i = blockIdx.x * blockDim.x + threadIdx.x;  // one per 8 elems
  const float* p = x + (size_t)i * 8;
  unsigned short tmp[8];
#pragma unroll
  for (int e = 0; e < 8; ++e) tmp[e] = f2bf(p[e]);
  *reinterpret_cast<u16x8*>(xb + (size_t)i * 8) = *reinterpret_cast<u16x8*>(tmp);
}

// ---- aggregate-first: Z[r][m][f] = sum_{e in bucket(r,n)} w_e * X[src_e][f]
// 16 lanes per m-row (j = lane&15 -> features j*8..j*8+7), 4 rows per wave.
// Z row stride per relation = Ms (padded to 128-multiple for the GEMM).
__global__ __launch_bounds__(256) void aggz_kernel(const unsigned short* __restrict__ X,
                                                   const int2* __restrict__ scb,
                                                   const int2* __restrict__ epay,
                                                   const int* __restrict__ qsrc,
                                                   const int* __restrict__ qdst,
                                                   unsigned short* __restrict__ Z,
                                                   int M, int Ms) {
  const int r = blockIdx.y;
  const int t = threadIdx.x;
  const int lane = t & 63;
  const int m = blockIdx.x * 16 + (t >> 6) * 4 + (lane >> 4);
  const int j = lane & 15;
  if (m >= M) return;
  int n = qsrc ? ((m < NQ) ? qsrc[m] : qdst[m - NQ]) : m;
  int2 meta = scb[r * NN + n];
  const int2* ep = epay + meta.x;
  const int c = meta.y;

  float ps[8];
#pragma unroll
  for (int k = 0; k < 8; ++k) ps[k] = 0.f;

  int i = 0;
  for (; i + 2 <= c; i += 2) {
    int2 p0 = ep[i], p1 = ep[i + 1];
    float w0 = __builtin_bit_cast(float, p0.y);
    float w1 = __builtin_bit_cast(float, p1.y);
    u16x8 v0 = *reinterpret_cast<const u16x8*>(X + ((size_t)p0.x << 7) + j * 8);
    u16x8 v1 = *reinterpret_cast<const u16x8*>(X + ((size_t)p1.x << 7) + j * 8);
#pragma unroll
    for (int k = 0; k < 8; ++k)
      ps[k] = fmaf(bf2f(v1[k]), w1, fmaf(bf2f(v0[k]), w0, ps[k]));
  }
  if (i < c) {
    int2 p0 = ep[i];
    float w0 = __builtin_bit_cast(float, p0.y);
    u16x8 v0 = *reinterpret_cast<const u16x8*>(X + ((size_t)p0.x << 7) + j * 8);
#pragma unroll
    for (int k = 0; k < 8; ++k) ps[k] = fmaf(bf2f(v0[k]), w0, ps[k]);
  }

  unsigned short tmp[8];
#pragma unroll
  for (int k = 0; k < 8; ++k) tmp[k] = f2bf(ps[k]);
  *reinterpret_cast<u16x8*>(Z + (((size_t)r * Ms + m) << 7) + j * 8) =
      *reinterpret_cast<u16x8*>(tmp);
}

// ---- fused K=384 GEMM with global_load_lds staging + 2-phase pipeline ----
// out[m] = tanh( sum_r Z[r][m] @ W_r + bsum ).
// 512 thr (8 waves, 2m x 4n). A-chunk (128x128 bf16 = 32KB) double-buffered in LDS,
// staged via global_load_lds width=16 with PRE-SWIZZLED global source
// (slot s -> s^(row&7)); MFMA ds_read applies the same XOR -> ~2-way conflicts (free).
// W fragments go global->reg (L2-hot, R9-proven pattern), issued BEFORE the stage
// issues so their vmcnt wait leaves the next chunk's loads in flight.
#define GBM 128
__global__ __launch_bounds__(512) void gemmp_kernel(const unsigned short* __restrict__ Z,
                                                    const unsigned short* __restrict__ Wt3,
                                                    const float* __restrict__ bsum,
                                                    void* __restrict__ outp,
                                                    int M, int Ms, int out_f32) {
  __shared__ unsigned short Abuf[2][GBM * F];   // 2 x 32 KB
  const int t = threadIdx.x;
  const int m0 = blockIdx.x * GBM;
  const int lane = t & 63, w = t >> 6;
  const int wm = w >> 2, wn = w & 3;            // 2m x 4n wave grid
  const int r0 = lane & 15, kq = lane >> 4;

  fx4 acc[4][2];
#pragma unroll
  for (int mt = 0; mt < 4; ++mt)
#pragma unroll
    for (int nt = 0; nt < 2; ++nt) acc[mt][nt] = (fx4){0.f, 0.f, 0.f, 0.f};

  // prologue: stage rel-0 chunk into buf 0 (rows m0..m0+127 are in-bounds: Ms padded)
  {
    const unsigned short* Zr = Z + (size_t)m0 * F;
#pragma unroll
    for (int i = 0; i < 4; ++i) {
      int slot = i * 512 + t;
      int row = slot >> 4, s = slot & 15;
      __builtin_amdgcn_global_load_lds(
          (const __attribute__((address_space(1))) uint32_t*)(
              Zr + ((size_t)row << 7) + ((s ^ (row & 7)) << 3)),
          (__attribute__((address_space(3))) uint32_t*)&Abuf[0][slot * 8], 16, 0, 0);
    }
  }
  __syncthreads();  // implicit vmcnt(0): buf0 ready

  int cur = 0;
  for (int r = 0; r < NREL; ++r) {
    // W_r fragments first (oldest outstanding loads -> compiler waits vmcnt(4))
    bf16x8 bfrag[2][4];
    const unsigned short* Wt = Wt3 + (size_t)r * F * F;
#pragma unroll
    for (int nt = 0; nt < 2; ++nt)
#pragma unroll
      for (int kb = 0; kb < 4; ++kb)
        bfrag[nt][kb] = __builtin_bit_cast(bf16x8,
            *reinterpret_cast<const u16x8*>(
                Wt + (wn * 32 + nt * 16 + r0) * F + (4 * kb + kq) * 8));

    // issue next chunk's stage into the other buffer (in flight during MFMA)
    if (r + 1 < NREL) {
      const unsigned short* Zr = Z + ((size_t)(r + 1) * Ms + m0) * F;
#pragma unroll
      for (int i = 0; i < 4; ++i) {
        int slot = i * 512 + t;
        int row = slot >> 4, s = slot & 15;
        __builtin_amdgcn_global_load_lds(
            (const __attribute__((address_space(1))) uint32_t*)(
                Zr + ((size_t)row << 7) + ((s ^ (row & 7)) << 3)),
            (__attribute__((address_space(3))) uint32_t*)&Abuf[cur ^ 1][slot * 8],
            16, 0, 0);
      }
    }

    // MFMA over this rel's K=128 from Abuf[cur] (swizzled read)
#pragma unroll
    for (int kb = 0; kb < 4; ++kb) {
      const int cs = ((kb * 4 + kq) ^ (r0 & 7)) * 8;
      bf16x8 a[4];
#pragma unroll
      for (int mt = 0; mt < 4; ++mt)
        a[mt] = __builtin_bit_cast(bf16x8,
            *reinterpret_cast<const u16x8*>(&Abuf[cur][(wm * 64 + mt * 16 + r0) * F + cs]));
#pragma unroll
      for (int mt = 0; mt < 4; ++mt)
#pragma unroll
        for (int nt = 0; nt < 2; ++nt)
          acc[mt][nt] = __builtin_amdgcn_mfma_f32_16x16x32_bf16(a[mt], bfrag[nt][kb],
                                                                acc[mt][nt], 0, 0, 0);
    }

    __syncthreads();  // implicit vmcnt(0): next buffer staged; this buffer's reads done
    cur ^= 1;
  }

  // epilogue: C/D layout col = lane&15, row = (lane>>4)*4 + reg; +bias, tanh
#pragma unroll
  for (int mt = 0; mt < 4; ++mt) {
    const int rbase = m0 + wm * 64 + mt * 16 + kq * 4;
#pragma unroll
    for (int nt = 0; nt < 2; ++nt) {
      int col = wn * 32 + nt * 16 + r0;
      float bb = bsum[col];
#pragma unroll
      for (int reg = 0; reg < 4; ++reg) {
        int gm = rbase + reg;
        if (gm < M) {
          float v = tanhf(acc[mt][nt][reg] + bb);
          if (out_f32) {
            ((float*)outp)[(size_t)gm * F + col] = v;
          } else {
            ((unsigned short*)outp)[(size_t)gm * F + col] = f2bf(v);
          }
        }
      }
    }
  }
}

extern "C" void kernel_launch(void* const* d_in, const int* in_sizes, int n_in,
                              void* d_out, int out_size, void* d_ws, size_t ws_size,
                              hipStream_t stream) {
  const float* emb = (const float*)d_in[0];
  const float* W1  = (const float*)d_in[1];
  const float* b1  = (const float*)d_in[2];
  const float* W2  = (const float*)d_in[3];
  const float* b2  = (const float*)d_in[4];
  const int* e_src = (const int*)d_in[5];
  const int* e_dst = (const int*)d_in[6];
  const int* qsrc  = (const int*)d_in[7];
  const int* qdst  = (const int*)d_in[8];
  float* out = (float*)d_out;

  const int MS1 = ((NN + GBM - 1) / GBM) * GBM;   // 100096 (padded Z stride, layer 1)
  const int MQ  = 2 * NQ;                          // 8192 (already 128-multiple)

  char* p = (char*)d_ws;
  size_t off = 0;
  auto take = [&](size_t n) { void* q = p + off; off = (off + n + 255) & ~(size_t)255; return q; };
  int* cnt    = (int*)take(2ull * NREL * NN * 4);       // [out|in] counts
  int* blksum = (int*)take((size_t)NSCANBLK * 4);       // scan block sums
  int2* scb   = (int2*)take((size_t)NBUCK * 8);         // {start, cnt} per bucket
  int* fill   = (int*)take((size_t)NBUCK * 4);
  int2* epay  = (int2*)take((size_t)NREL * NE * 8);     // {src, w}
  unsigned short* Wtb = (unsigned short*)take(2ull * NREL * F * F * 2);
  float* bsum = (float*)take(2ull * F * 4);
  unsigned short* Xb  = (unsigned short*)take((size_t)NN * F * 2);   // h0 / h1 (bf16)
  unsigned short* Z   = (unsigned short*)take((size_t)NREL * MS1 * F * 2);

  int* cnt_in = cnt + (size_t)NREL * NN;

  hipMemsetAsync(cnt, 0, 2ull * NREL * NN * 4, stream);
  cnt_kernel<<<(NREL * NE + 255) / 256, 256, 0, stream>>>(e_src, e_dst, cnt);
  scanA_kernel<<<NSCANBLK, 256, 0, stream>>>(cnt_in, blksum);
  scanB_kernel<<<1, 64, 0, stream>>>(blksum);
  scanC_kernel<<<NSCANBLK, 256, 0, stream>>>(cnt_in, blksum, scb, fill);
  fill_kernel<<<(NREL * NE + 255) / 256, 256, 0, stream>>>(e_src, e_dst, cnt, scb, fill, epay);
  wcvt_kernel<<<(2 * NREL * F * F + 255) / 256, 256, 0, stream>>>(W1, W2, Wtb);
  bias_kernel<<<1, 256, 0, stream>>>(b1, b2, bsum);
  cvtx_kernel<<<(NN * F / 8 + 255) / 256, 256, 0, stream>>>(emb, Xb);

  // layer 1: Z1 at all nodes, pipelined GEMM writes bf16 h1 back into Xb
  dim3 ag1((NN + 15) / 16, NREL);
  aggz_kernel<<<ag1, 256, 0, stream>>>(Xb, scb, epay, nullptr, nullptr, Z, NN, MS1);
  gemmp_kernel<<<MS1 / GBM, 512, 0, stream>>>(Z, Wtb, bsum, Xb, NN, MS1, 0);

  // layer 2: only the 2*NQ query slots
  dim3 ag2((MQ + 15) / 16, NREL);
  aggz_kernel<<<ag2, 256, 0, stream>>>(Xb, scb, epay, qsrc, qdst, Z, MQ, MQ);
  gemmp_kernel<<<MQ / GBM, 512, 0, stream>>>(
      Z, Wtb + (size_t)NREL * F * F, bsum + F, out, MQ, MQ, 1);
}